// Round 5
// baseline (481.048 us; speedup 1.0000x reference)
//
#include <hip/hip_runtime.h>
#include <math.h>

typedef __bf16 bf16;
typedef __bf16 bf16x4 __attribute__((ext_vector_type(4)));
typedef __bf16 bf16x8 __attribute__((ext_vector_type(8)));
typedef float  f32x4  __attribute__((ext_vector_type(4)));

__device__ __forceinline__ f32x4 mfma16x16x32(bf16x8 a, bf16x8 b, f32x4 c) {
  return __builtin_amdgcn_mfma_f32_16x16x32_bf16(a, b, c, 0, 0, 0);
}

// async 16B global -> LDS (lane data lands at ldsbase + lane*16)
__device__ __forceinline__ void async16(const bf16* gp, bf16* lp) {
  __builtin_amdgcn_global_load_lds(
      (const __attribute__((address_space(1))) void*)gp,
      (__attribute__((address_space(3))) void*)lp, 16, 0, 0);
}

// ---------------- fp32 -> bf16 convert ----------------
__global__ void __launch_bounds__(256) convert_bf16_kernel(const float* __restrict__ in,
                                                           bf16* __restrict__ out, int n4) {
  int i = blockIdx.x * 256 + threadIdx.x;
  if (i < n4) {
    float4 f = ((const float4*)in)[i];
    bf16x4 b = {(bf16)f.x, (bf16)f.y, (bf16)f.z, (bf16)f.w};
    ((bf16x4*)out)[i] = b;
  }
}

// w3 [67735][16] fp32 -> W3b [67840][32] bf16, k 16..31 zeroed
__global__ void __launch_bounds__(256) convert_w3_kernel(const float* __restrict__ w3,
                                                         bf16* __restrict__ W3b, int n4) {
  int i = blockIdx.x * 256 + threadIdx.x;
  if (i >= n4) return;
  int row = i >> 2, kq = i & 3;
  float4 f = *(const float4*)&w3[(size_t)i * 4];
  bf16x4 b = {(bf16)f.x, (bf16)f.y, (bf16)f.z, (bf16)f.w};
  *(bf16x4*)&W3b[(size_t)row * 32 + kq * 4] = b;
  bf16x4 z = {(bf16)0.f, (bf16)0.f, (bf16)0.f, (bf16)0.f};
  *(bf16x4*)&W3b[(size_t)row * 32 + 16 + kq * 4] = z;
}

// P [1024][dX] fp32 -> Pt [*][1024] bf16 (transpose+convert, zero-pad cols>=dX)
__global__ void __launch_bounds__(256) transpose_convert_kernel(const float* __restrict__ P,
                                                                bf16* __restrict__ Pt, int dX) {
  __shared__ float t[32][33];
  int tx = threadIdx.x & 31, ty = threadIdx.x >> 5;
  int k0 = blockIdx.x * 32, c0 = blockIdx.y * 32;
#pragma unroll
  for (int s = 0; s < 4; ++s) {
    int k = k0 + ty + s * 8, col = c0 + tx;
    t[ty + s * 8][tx] = (col < dX) ? P[(size_t)k * dX + col] : 0.f;
  }
  __syncthreads();
#pragma unroll
  for (int s = 0; s < 4; ++s) {
    int colo = c0 + ty + s * 8;
    Pt[(size_t)colo * 1024 + k0 + tx] = (bf16)t[tx][ty + s * 8];
  }
}

// ---------------- row compaction by target cluster ----------------
__global__ void __launch_bounds__(1024) compact_kernel(const int* __restrict__ target,
                                                       int* __restrict__ rowmap,
                                                       int* __restrict__ slotmap,
                                                       int* __restrict__ counts) {
  __shared__ int cnt[3];
  int tid = threadIdx.x;
  if (tid < 3) cnt[tid] = 0;
  for (int i = tid; i < 3 * 1152; i += 1024) rowmap[i] = 0;
  __syncthreads();
  int t = target[tid];
  int c = (t >= 200000) ? 2 : (t >= 40000) ? 1 : (t >= 20000) ? 0 : -1;
  int slot = -1;
  if (c >= 0) {
    slot = atomicAdd(&cnt[c], 1);
    rowmap[c * 1152 + slot] = tid;
  }
  slotmap[tid] = slot;
  __syncthreads();
  if (tid < 3) counts[tid] = cnt[tid];
}

// ---------------- unified MFMA GEMM (128x128 tile, async staging) ----------------
// LSE=true: direct sumexp (no max - logits are O(1)) atomically added per row.
template <int KDIM, bool LSE>
__global__ void __launch_bounds__(256) gemm_kernel(
    const bf16* __restrict__ A, int strideA,
    const int* __restrict__ rmap, const int* __restrict__ cntp,
    const bf16* __restrict__ B,
    const float* __restrict__ bias, const float* __restrict__ bias2,
    int splice, int V, float* __restrict__ sums, int nchunk,
    bf16* __restrict__ Out, int strideOut, int dX) {
  constexpr int BK = (KDIM < 64) ? KDIM : 64;
  constexpr int KG = BK / 8;
  constexpr int NIT = KDIM / BK;
  __shared__ bf16 Alds[128 * BK];
  __shared__ bf16 Blds[128 * BK];

  const int tid = threadIdx.x;
  const int w = tid >> 6, lane = tid & 63;
  const int q = lane >> 4, c = lane & 15;
  const int wr = w >> 1, wc = w & 1;

  int f = blockIdx.x;
  int xr = f & 7, rb = (f >> 3) & 7, cq = f >> 6;
  int chunk = cq * 8 + xr;
  if (chunk >= nchunk) return;
  const int row0 = rb * 128, col0 = chunk * 128;
  if (cntp && row0 >= *cntp) return;

  int arow[KG / 2];
#pragma unroll
  for (int i = 0; i < KG / 2; ++i) {
    int g = i * 256 + tid;
    int r = row0 + g / KG;
    arow[i] = rmap ? rmap[r] : r;
  }

  f32x4 acc[4][4] = {};

  for (int kt = 0; kt < NIT; ++kt) {
    const int k0 = kt * BK;
#pragma unroll
    for (int i = 0; i < KG / 2; ++i) {
      int g = i * 256 + tid;
      int col = g / KG, j = g % KG;
      int kg = (KG == 8) ? (j ^ (col & 7)) : (j ^ ((col >> 1) & 3));
      async16(A + (size_t)arow[i] * strideA + k0 + kg * 8, &Alds[(size_t)(g & ~63) * 8]);
      async16(B + (size_t)(col0 + col) * KDIM + k0 + kg * 8, &Blds[(size_t)(g & ~63) * 8]);
    }
    __syncthreads();
#pragma unroll
    for (int ks = 0; ks < BK / 32; ++ks) {
      bf16x8 af[4], bfr[4];
#pragma unroll
      for (int rt = 0; rt < 4; ++rt) {
        int rl = wr * 64 + rt * 16 + c;
        int kq = ks * 4 + q;
        int kg = (KG == 8) ? (kq ^ (rl & 7)) : (kq ^ ((rl >> 1) & 3));
        af[rt] = *(const bf16x8*)&Alds[((size_t)rl * KG + kg) * 8];
      }
#pragma unroll
      for (int ct = 0; ct < 4; ++ct) {
        int cl = wc * 64 + ct * 16 + c;
        int kq = ks * 4 + q;
        int kg = (KG == 8) ? (kq ^ (cl & 7)) : (kq ^ ((cl >> 1) & 3));
        bfr[ct] = *(const bf16x8*)&Blds[((size_t)cl * KG + kg) * 8];
      }
#pragma unroll
      for (int rt = 0; rt < 4; ++rt)
#pragma unroll
        for (int ct = 0; ct < 4; ++ct)
          acc[rt][ct] = mfma16x16x32(af[rt], bfr[ct], acc[rt][ct]);
    }
    __syncthreads();
  }

  if (!LSE) {
#pragma unroll
    for (int rt = 0; rt < 4; ++rt)
#pragma unroll
      for (int ct = 0; ct < 4; ++ct)
#pragma unroll
        for (int r = 0; r < 4; ++r) {
          int col = col0 + wc * 64 + ct * 16 + c;
          if (col < dX) {
            int row = row0 + wr * 64 + rt * 16 + q * 4 + r;
            Out[(size_t)row * strideOut + col] = (bf16)acc[rt][ct][r];
          }
        }
    return;
  }

  // direct-sum epilogue: exp(logit) accumulated, one shuffle-reduce + atomic
  float bv[4];
#pragma unroll
  for (int ct = 0; ct < 4; ++ct) {
    int colg = col0 + wc * 64 + ct * 16 + c;
    bv[ct] = (colg < V) ? ((colg < splice) ? bias[colg] : bias2[colg - splice]) : -INFINITY;
  }
#pragma unroll
  for (int rt = 0; rt < 4; ++rt) {
#pragma unroll
    for (int r = 0; r < 4; ++r) {
      float s = __expf(acc[rt][0][r] + bv[0]) + __expf(acc[rt][1][r] + bv[1]) +
                __expf(acc[rt][2][r] + bv[2]) + __expf(acc[rt][3][r] + bv[3]);
#pragma unroll
      for (int off = 1; off <= 8; off <<= 1) s += __shfl_xor(s, off);
      if (c == 0) atomicAdd(&sums[row0 + wr * 64 + rt * 16 + q * 4 + r], s);
    }
  }
}

// ---------------- tail LSE: A resident in LDS, CPB chunks/block, dbuf B ----------------
template <int KDIM, int CPB>
__global__ void __launch_bounds__(256) tail_lse_kernel(
    const bf16* __restrict__ A, int strideA,
    const int* __restrict__ rmap, const int* __restrict__ cntp,
    const bf16* __restrict__ B, const float* __restrict__ bias,
    int V, float* __restrict__ sums, int nchunk) {
  constexpr int KG = KDIM / 8;              // 4 or 8
  constexpr int APT = 128 * KG / 256;       // granules per thread (2 or 4)
  __shared__ bf16 Alds[128 * KDIM];
  __shared__ bf16 Blds[2][128 * KDIM];

  const int tid = threadIdx.x;
  const int w = tid >> 6, lane = tid & 63;
  const int q = lane >> 4, c = lane & 15;
  const int wr = w >> 1, wc = w & 1;

  int f = blockIdx.x;
  int xr = f & 7, rb = (f >> 3) & 7, gq = f >> 6;
  int grp = gq * 8 + xr;
  int chunk0 = grp * CPB;
  if (chunk0 >= nchunk) return;
  const int row0 = rb * 128;
  if (row0 >= *cntp) return;

  int arow[APT];
#pragma unroll
  for (int i = 0; i < APT; ++i) {
    int g = i * 256 + tid;
    arow[i] = rmap[row0 + g / KG];
  }

  auto stageB = [&](int ch, int b) {
#pragma unroll
    for (int i = 0; i < APT; ++i) {
      int g = i * 256 + tid;
      int col = g / KG, j = g % KG;
      int kg = (KG == 8) ? (j ^ (col & 7)) : (j ^ ((col >> 1) & 3));
      async16(B + ((size_t)ch * 128 + col) * KDIM + kg * 8, &Blds[b][(size_t)(g & ~63) * 8]);
    }
  };

  // prologue: stage A + B0
#pragma unroll
  for (int i = 0; i < APT; ++i) {
    int g = i * 256 + tid;
    int col = g / KG, j = g % KG;
    int kg = (KG == 8) ? (j ^ (col & 7)) : (j ^ ((col >> 1) & 3));
    async16(A + (size_t)arow[i] * strideA + kg * 8, &Alds[(size_t)(g & ~63) * 8]);
  }
  stageB(chunk0, 0);
  __syncthreads();

  float s[16] = {};

  for (int cc = 0; cc < CPB; ++cc) {
    int ch = chunk0 + cc;
    bool valid = ch < nchunk;
    if (cc + 1 < CPB && chunk0 + cc + 1 < nchunk) stageB(chunk0 + cc + 1, (cc + 1) & 1);
    if (valid) {
      f32x4 acc[4][4] = {};
#pragma unroll
      for (int ks = 0; ks < KDIM / 32; ++ks) {
        bf16x8 af[4], bfr[4];
#pragma unroll
        for (int rt = 0; rt < 4; ++rt) {
          int rl = wr * 64 + rt * 16 + c;
          int kq = ks * 4 + q;
          int kg = (KG == 8) ? (kq ^ (rl & 7)) : (kq ^ ((rl >> 1) & 3));
          af[rt] = *(const bf16x8*)&Alds[((size_t)rl * KG + kg) * 8];
        }
#pragma unroll
        for (int ct = 0; ct < 4; ++ct) {
          int cl = wc * 64 + ct * 16 + c;
          int kq = ks * 4 + q;
          int kg = (KG == 8) ? (kq ^ (cl & 7)) : (kq ^ ((cl >> 1) & 3));
          bfr[ct] = *(const bf16x8*)&Blds[cc & 1][((size_t)cl * KG + kg) * 8];
        }
#pragma unroll
        for (int rt = 0; rt < 4; ++rt)
#pragma unroll
          for (int ct = 0; ct < 4; ++ct)
            acc[rt][ct] = mfma16x16x32(af[rt], bfr[ct], acc[rt][ct]);
      }
      float bv[4];
#pragma unroll
      for (int ct = 0; ct < 4; ++ct) {
        int colg = ch * 128 + wc * 64 + ct * 16 + c;
        bv[ct] = (colg < V) ? bias[colg] : -INFINITY;
      }
#pragma unroll
      for (int rt = 0; rt < 4; ++rt)
#pragma unroll
        for (int r = 0; r < 4; ++r)
          s[rt * 4 + r] += __expf(acc[rt][0][r] + bv[0]) + __expf(acc[rt][1][r] + bv[1]) +
                           __expf(acc[rt][2][r] + bv[2]) + __expf(acc[rt][3][r] + bv[3]);
    }
    __syncthreads();
  }

#pragma unroll
  for (int i = 0; i < 16; ++i) {
    float v = s[i];
#pragma unroll
    for (int off = 1; off <= 8; off <<= 1) v += __shfl_xor(v, off);
    if (c == 0) atomicAdd(&sums[row0 + wr * 64 + (i >> 2) * 16 + q * 4 + (i & 3)], v);
  }
}

// ---------------- final combine ----------------
__device__ __forceinline__ float wave_sum64(float v) {
#pragma unroll
  for (int off = 1; off < 64; off <<= 1) v += __shfl_xor(v, off);
  return v;
}
__device__ float dot_bw(const bf16* __restrict__ h, const float* __restrict__ wv, int K) {
  int lane = threadIdx.x & 63;
  float s = 0.f;
  for (int i = lane; i < K; i += 64) s += (float)h[i] * wv[i];
  return wave_sum64(s);
}

__global__ void __launch_bounds__(256) final_kernel(
    const int* __restrict__ target, const int* __restrict__ slotmap,
    const float* __restrict__ sumH, const float* __restrict__ sum1,
    const float* __restrict__ sum2, const float* __restrict__ sum3,
    const bf16* __restrict__ Hcat,
    const float* __restrict__ head_w, const float* __restrict__ head_b,
    const float* __restrict__ cluster_w, const float* __restrict__ cluster_b,
    const float* __restrict__ w1, const float* __restrict__ b1,
    const float* __restrict__ w2, const float* __restrict__ b2,
    const float* __restrict__ w3, const float* __restrict__ b3,
    float* __restrict__ out) {
  int wv = threadIdx.x >> 6, lane = threadIdx.x & 63;
  int row = blockIdx.x * 4 + wv;
  int t = target[row];
  const bf16* h0 = Hcat + (size_t)row * 1408;

  float lseH = __logf(sumH[row]);
  float lp;
  if (t < 20000) {
    float sel = dot_bw(h0, head_w + (size_t)t * 1024, 1024) + head_b[t];
    lp = sel - lseH;
  } else {
    int i, L, KW, hoff;
    const float* sp; const float* W; const float* Bb;
    if (t < 40000)        { i = 1; L = 20000;  KW = 256; hoff = 1024; sp = sum1; W = w1; Bb = b1; }
    else if (t < 200000)  { i = 2; L = 40000;  KW = 64;  hoff = 1280; sp = sum2; W = w2; Bb = b2; }
    else                  { i = 3; L = 200000; KW = 16;  hoff = 1344; sp = sum3; W = w3; Bb = b3; }
    int slot = slotmap[row];
    float lseT = __logf(sp[slot]);
    int ti = t - L;
    float tsel = dot_bw(h0 + hoff, W + (size_t)ti * KW, KW) + Bb[ti];
    int j = 3 - i;  // head_lp[:, -i] == cluster row (3-i)
    float csel = dot_bw(h0, cluster_w + (size_t)j * 1024, 1024) + cluster_b[j];
    lp = (csel - lseH) + (tsel - lseT);
  }
  if (lane == 0) out[row] = -lp;
}

extern "C" void kernel_launch(void* const* d_in, const int* in_sizes, int n_in,
                              void* d_out, int out_size, void* d_ws, size_t ws_size,
                              hipStream_t stream) {
  (void)in_sizes; (void)n_in; (void)out_size; (void)ws_size;
  const float* hidden    = (const float*)d_in[0];
  const int*   target    = (const int*)d_in[1];
  const float* head_w    = (const float*)d_in[2];
  const float* head_b    = (const float*)d_in[3];
  const float* cluster_w = (const float*)d_in[4];
  const float* cluster_b = (const float*)d_in[5];
  const float* proj0     = (const float*)d_in[6];
  const float* proj1     = (const float*)d_in[7];
  const float* proj2     = (const float*)d_in[8];
  const float* proj3     = (const float*)d_in[9];
  const float* w1 = (const float*)d_in[10];
  const float* b1 = (const float*)d_in[11];
  const float* w2 = (const float*)d_in[12];
  const float* b2 = (const float*)d_in[13];
  const float* w3 = (const float*)d_in[14];
  const float* b3 = (const float*)d_in[15];
  float* out = (float*)d_out;

  char* p = (char*)d_ws;
  bf16* hid_b = (bf16*)p; p += (size_t)1024 * 1024 * 2;
  bf16* Hcat  = (bf16*)p; p += (size_t)1024 * 1408 * 2;  // h0|h1|h2|h3 stride 1408
  bf16* Pcat  = (bf16*)p; p += (size_t)1408 * 1024 * 2;
  bf16* Wh    = (bf16*)p; p += (size_t)20096 * 1024 * 2; // head_w ++ cluster_w
  bf16* W1b   = (bf16*)p; p += (size_t)20096 * 256 * 2;
  bf16* W2b   = (bf16*)p; p += (size_t)160000 * 64 * 2;
  bf16* W3b   = (bf16*)p; p += (size_t)67840 * 32 * 2;
  float* sumH = (float*)p; p += 1024 * 4;
  float* sum1 = (float*)p; p += 1152 * 4;
  float* sum2 = (float*)p; p += 1152 * 4;
  float* sum3 = (float*)p; p += 1152 * 4;
  int* rowmap = (int*)p;  p += 3 * 1152 * 4;
  int* slotmap= (int*)p;  p += 1024 * 4;
  int* counts = (int*)p;  p += 3 * 4;

  hipMemsetAsync(sumH, 0, (1024 + 3 * 1152) * 4, stream);
  compact_kernel<<<1, 1024, 0, stream>>>(target, rowmap, slotmap, counts);

  // ---- weight/input conversion ----
  convert_bf16_kernel<<<1024, 256, 0, stream>>>(hidden, hid_b, 262144);
  convert_bf16_kernel<<<20000, 256, 0, stream>>>(head_w, Wh, 5120000);
  convert_bf16_kernel<<<3, 256, 0, stream>>>(cluster_w, Wh + (size_t)20000 * 1024, 768);
  convert_bf16_kernel<<<5000, 256, 0, stream>>>(w1, W1b, 1280000);
  convert_bf16_kernel<<<10000, 256, 0, stream>>>(w2, W2b, 2560000);
  convert_w3_kernel<<<1059, 256, 0, stream>>>(w3, W3b, 270940);
  transpose_convert_kernel<<<dim3(32, 32), 256, 0, stream>>>(proj0, Pcat, 1024);
  transpose_convert_kernel<<<dim3(32, 8), 256, 0, stream>>>(proj1, Pcat + (size_t)1024 * 1024, 256);
  transpose_convert_kernel<<<dim3(32, 2), 256, 0, stream>>>(proj2, Pcat + (size_t)1280 * 1024, 64);
  transpose_convert_kernel<<<dim3(32, 1), 256, 0, stream>>>(proj3, Pcat + (size_t)1344 * 1024, 16);

  // ---- all projections in one GEMM: Hcat[1024][1376] = hid_b @ Pcat^T ----
  gemm_kernel<1024, false><<<128, 256, 0, stream>>>(hid_b, 1024, nullptr, nullptr, Pcat,
                                                    nullptr, nullptr, 0, 0, nullptr, 11,
                                                    Hcat, 1408, 1376);

  // ---- fused GEMM + sumexp ----
  gemm_kernel<1024, true><<<64 * 20, 256, 0, stream>>>(Hcat, 1408, nullptr, nullptr, Wh,
                                                       head_b, cluster_b, 20000, 20003,
                                                       sumH, 157, nullptr, 0, 0);
  gemm_kernel<256, true><<<64 * 20, 256, 0, stream>>>(Hcat + 1024, 1408, rowmap, counts, W1b,
                                                      b1, b1, 0x40000000, 20000,
                                                      sum1, 157, nullptr, 0, 0);
  tail_lse_kernel<64, 10><<<64 * 16, 256, 0, stream>>>(Hcat + 1280, 1408, rowmap + 1152,
                                                       counts + 1, W2b, b2, 160000, sum2, 1250);
  tail_lse_kernel<32, 4><<<64 * 17, 256, 0, stream>>>(Hcat + 1344, 1408, rowmap + 2304,
                                                      counts + 2, W3b, b3, 67735, sum3, 530);

  final_kernel<<<256, 256, 0, stream>>>(target, slotmap, sumH, sum1, sum2, sum3, Hcat,
                                        head_w, head_b, cluster_w, cluster_b,
                                        w1, b1, w2, b2, w3, b3, out);
}

// Round 6
// 471.175 us; speedup vs baseline: 1.0210x; 1.0210x over previous
//
#include <hip/hip_runtime.h>
#include <math.h>

typedef __bf16 bf16;
typedef __bf16 bf16x4 __attribute__((ext_vector_type(4)));
typedef __bf16 bf16x8 __attribute__((ext_vector_type(8)));
typedef float  f32x4  __attribute__((ext_vector_type(4)));

__device__ __forceinline__ f32x4 mfma16x16x32(bf16x8 a, bf16x8 b, f32x4 c) {
  return __builtin_amdgcn_mfma_f32_16x16x32_bf16(a, b, c, 0, 0, 0);
}

// async 16B global -> LDS (lane data lands at ldsbase + lane*16)
__device__ __forceinline__ void async16(const bf16* gp, bf16* lp) {
  __builtin_amdgcn_global_load_lds(
      (const __attribute__((address_space(1))) void*)gp,
      (__attribute__((address_space(3))) void*)lp, 16, 0, 0);
}

// ---------------- fused fp32 -> bf16 convert of all plain weight blobs ----------------
// segments (float4 units): hidden 262144 | head_w 5120000 | cluster_w 768 | w1 1280000 | w2 2560000
__global__ void __launch_bounds__(256) convert_all_kernel(
    const float* __restrict__ hidden, const float* __restrict__ head_w,
    const float* __restrict__ cluster_w, const float* __restrict__ w1,
    const float* __restrict__ w2,
    bf16* __restrict__ hid_b, bf16* __restrict__ Wh,
    bf16* __restrict__ W1b, bf16* __restrict__ W2b) {
  constexpr int O0 = 262144, O1 = O0 + 5120000, O2 = O1 + 768,
                O3 = O2 + 1280000, O4 = O3 + 2560000;
  int i = blockIdx.x * 256 + threadIdx.x;
  if (i >= O4) return;
  const float* src; bf16* dst; int rel;
  if (i < O0)      { src = hidden;    dst = hid_b;                      rel = i; }
  else if (i < O1) { src = head_w;    dst = Wh;                         rel = i - O0; }
  else if (i < O2) { src = cluster_w; dst = Wh + (size_t)20000 * 1024;  rel = i - O1; }
  else if (i < O3) { src = w1;        dst = W1b;                        rel = i - O2; }
  else             { src = w2;        dst = W2b;                        rel = i - O3; }
  float4 f = ((const float4*)src)[rel];
  bf16x4 b = {(bf16)f.x, (bf16)f.y, (bf16)f.z, (bf16)f.w};
  ((bf16x4*)dst)[rel] = b;
}

// w3 [67735][16] fp32 -> W3b [67840][32] bf16, k 16..31 zeroed
__global__ void __launch_bounds__(256) convert_w3_kernel(const float* __restrict__ w3,
                                                         bf16* __restrict__ W3b, int n4) {
  int i = blockIdx.x * 256 + threadIdx.x;
  if (i >= n4) return;
  int row = i >> 2, kq = i & 3;
  float4 f = *(const float4*)&w3[(size_t)i * 4];
  bf16x4 b = {(bf16)f.x, (bf16)f.y, (bf16)f.z, (bf16)f.w};
  *(bf16x4*)&W3b[(size_t)row * 32 + kq * 4] = b;
  bf16x4 z = {(bf16)0.f, (bf16)0.f, (bf16)0.f, (bf16)0.f};
  *(bf16x4*)&W3b[(size_t)row * 32 + 16 + kq * 4] = z;
}

// all 4 projections: P [1024][dX] fp32 -> Pt [*][1024] bf16 (transpose+convert, zero-pad)
__global__ void __launch_bounds__(256) transpose_all_kernel(
    const float* __restrict__ proj0, const float* __restrict__ proj1,
    const float* __restrict__ proj2, const float* __restrict__ proj3,
    bf16* __restrict__ Pcat) {
  __shared__ float t[32][33];
  int y = blockIdx.y;
  const float* P; bf16* Pt; int dX, c0;
  if (y < 32)      { P = proj0; Pt = Pcat;                        dX = 1024; c0 = y * 32; }
  else if (y < 40) { P = proj1; Pt = Pcat + (size_t)1024 * 1024;  dX = 256;  c0 = (y - 32) * 32; }
  else if (y < 42) { P = proj2; Pt = Pcat + (size_t)1280 * 1024;  dX = 64;   c0 = (y - 40) * 32; }
  else             { P = proj3; Pt = Pcat + (size_t)1344 * 1024;  dX = 16;   c0 = 0; }
  int tx = threadIdx.x & 31, ty = threadIdx.x >> 5;
  int k0 = blockIdx.x * 32;
#pragma unroll
  for (int s = 0; s < 4; ++s) {
    int k = k0 + ty + s * 8, col = c0 + tx;
    t[ty + s * 8][tx] = (col < dX) ? P[(size_t)k * dX + col] : 0.f;
  }
  __syncthreads();
#pragma unroll
  for (int s = 0; s < 4; ++s) {
    int colo = c0 + ty + s * 8;
    Pt[(size_t)colo * 1024 + k0 + tx] = (bf16)t[tx][ty + s * 8];
  }
}

// ---------------- row compaction by target cluster (+ zero sums) ----------------
__global__ void __launch_bounds__(1024) compact_kernel(const int* __restrict__ target,
                                                       int* __restrict__ rowmap,
                                                       int* __restrict__ slotmap,
                                                       int* __restrict__ counts,
                                                       float* __restrict__ sums_zero) {
  __shared__ int cnt[3];
  int tid = threadIdx.x;
  if (tid < 3) cnt[tid] = 0;
  for (int i = tid; i < 3 * 1152; i += 1024) rowmap[i] = 0;
  for (int i = tid; i < 1024 + 3 * 1152; i += 1024) sums_zero[i] = 0.f;
  __syncthreads();
  int t = target[tid];
  int c = (t >= 200000) ? 2 : (t >= 40000) ? 1 : (t >= 20000) ? 0 : -1;
  int slot = -1;
  if (c >= 0) {
    slot = atomicAdd(&cnt[c], 1);
    rowmap[c * 1152 + slot] = tid;
  }
  slotmap[tid] = slot;
  __syncthreads();
  if (tid < 3) counts[tid] = cnt[tid];
}

// ---------------- unified MFMA GEMM, double-buffered K-loop ----------------
// stage(k+1) issued BEFORE compute(k): the pre-barrier vmcnt drain is covered by MFMA.
template <int KDIM, bool LSE>
__global__ void __launch_bounds__(256) gemm_kernel(
    const bf16* __restrict__ A, int strideA,
    const int* __restrict__ rmap, const int* __restrict__ cntp,
    const bf16* __restrict__ B,
    const float* __restrict__ bias, const float* __restrict__ bias2,
    int splice, int V, float* __restrict__ sums, int nchunk,
    bf16* __restrict__ Out, int strideOut, int dX) {
  constexpr int BK = (KDIM < 64) ? KDIM : 64;
  constexpr int KG = BK / 8;
  constexpr int NIT = KDIM / BK;
  __shared__ bf16 Alds[2][128 * BK];
  __shared__ bf16 Blds[2][128 * BK];

  const int tid = threadIdx.x;
  const int w = tid >> 6, lane = tid & 63;
  const int q = lane >> 4, c = lane & 15;
  const int wr = w >> 1, wc = w & 1;

  int f = blockIdx.x;
  int xr = f & 7, rb = (f >> 3) & 7, cq = f >> 6;
  int chunk = cq * 8 + xr;
  if (chunk >= nchunk) return;
  const int row0 = rb * 128, col0 = chunk * 128;
  if (cntp && row0 >= *cntp) return;

  int arow[KG / 2];
#pragma unroll
  for (int i = 0; i < KG / 2; ++i) {
    int g = i * 256 + tid;
    int r = row0 + g / KG;
    arow[i] = rmap ? rmap[r] : r;
  }

  auto stage = [&](int kt, int b) {
    const int k0 = kt * BK;
#pragma unroll
    for (int i = 0; i < KG / 2; ++i) {
      int g = i * 256 + tid;
      int col = g / KG, j = g % KG;
      int kg = (KG == 8) ? (j ^ (col & 7)) : (j ^ ((col >> 1) & 3));
      async16(A + (size_t)arow[i] * strideA + k0 + kg * 8, &Alds[b][(size_t)(g & ~63) * 8]);
      async16(B + (size_t)(col0 + col) * KDIM + k0 + kg * 8, &Blds[b][(size_t)(g & ~63) * 8]);
    }
  };

  f32x4 acc[4][4] = {};
  stage(0, 0);
  __syncthreads();

  for (int kt = 0; kt < NIT; ++kt) {
    const int cur = kt & 1;
    if (kt + 1 < NIT) stage(kt + 1, cur ^ 1);
#pragma unroll
    for (int ks = 0; ks < BK / 32; ++ks) {
      bf16x8 af[4], bfr[4];
#pragma unroll
      for (int rt = 0; rt < 4; ++rt) {
        int rl = wr * 64 + rt * 16 + c;
        int kq = ks * 4 + q;
        int kg = (KG == 8) ? (kq ^ (rl & 7)) : (kq ^ ((rl >> 1) & 3));
        af[rt] = *(const bf16x8*)&Alds[cur][((size_t)rl * KG + kg) * 8];
      }
#pragma unroll
      for (int ct = 0; ct < 4; ++ct) {
        int cl = wc * 64 + ct * 16 + c;
        int kq = ks * 4 + q;
        int kg = (KG == 8) ? (kq ^ (cl & 7)) : (kq ^ ((cl >> 1) & 3));
        bfr[ct] = *(const bf16x8*)&Blds[cur][((size_t)cl * KG + kg) * 8];
      }
#pragma unroll
      for (int rt = 0; rt < 4; ++rt)
#pragma unroll
        for (int ct = 0; ct < 4; ++ct)
          acc[rt][ct] = mfma16x16x32(af[rt], bfr[ct], acc[rt][ct]);
    }
    __syncthreads();
  }

  if (!LSE) {
#pragma unroll
    for (int rt = 0; rt < 4; ++rt)
#pragma unroll
      for (int ct = 0; ct < 4; ++ct)
#pragma unroll
        for (int r = 0; r < 4; ++r) {
          int col = col0 + wc * 64 + ct * 16 + c;
          if (col < dX) {
            int row = row0 + wr * 64 + rt * 16 + q * 4 + r;
            Out[(size_t)row * strideOut + col] = (bf16)acc[rt][ct][r];
          }
        }
    return;
  }

  // direct-sum epilogue (logits O(1): no max needed); one shuffle-reduce + atomic
  float bv[4];
#pragma unroll
  for (int ct = 0; ct < 4; ++ct) {
    int colg = col0 + wc * 64 + ct * 16 + c;
    bv[ct] = (colg < V) ? ((colg < splice) ? bias[colg] : bias2[colg - splice]) : -INFINITY;
  }
#pragma unroll
  for (int rt = 0; rt < 4; ++rt) {
#pragma unroll
    for (int r = 0; r < 4; ++r) {
      float s = __expf(acc[rt][0][r] + bv[0]) + __expf(acc[rt][1][r] + bv[1]) +
                __expf(acc[rt][2][r] + bv[2]) + __expf(acc[rt][3][r] + bv[3]);
#pragma unroll
      for (int off = 1; off <= 8; off <<= 1) s += __shfl_xor(s, off);
      if (c == 0) atomicAdd(&sums[row0 + wr * 64 + rt * 16 + q * 4 + r], s);
    }
  }
}

// ---------------- tail LSE: A resident in LDS, CPB chunks/block, dbuf B ----------------
template <int KDIM, int CPB>
__global__ void __launch_bounds__(256) tail_lse_kernel(
    const bf16* __restrict__ A, int strideA,
    const int* __restrict__ rmap, const int* __restrict__ cntp,
    const bf16* __restrict__ B, const float* __restrict__ bias,
    int V, float* __restrict__ sums, int nchunk) {
  constexpr int KG = KDIM / 8;
  constexpr int APT = 128 * KG / 256;
  __shared__ bf16 Alds[128 * KDIM];
  __shared__ bf16 Blds[2][128 * KDIM];

  const int tid = threadIdx.x;
  const int w = tid >> 6, lane = tid & 63;
  const int q = lane >> 4, c = lane & 15;
  const int wr = w >> 1, wc = w & 1;

  int f = blockIdx.x;
  int xr = f & 7, rb = (f >> 3) & 7, gq = f >> 6;
  int grp = gq * 8 + xr;
  int chunk0 = grp * CPB;
  if (chunk0 >= nchunk) return;
  const int row0 = rb * 128;
  if (row0 >= *cntp) return;

  int arow[APT];
#pragma unroll
  for (int i = 0; i < APT; ++i) {
    int g = i * 256 + tid;
    arow[i] = rmap[row0 + g / KG];
  }

  auto stageB = [&](int ch, int b) {
#pragma unroll
    for (int i = 0; i < APT; ++i) {
      int g = i * 256 + tid;
      int col = g / KG, j = g % KG;
      int kg = (KG == 8) ? (j ^ (col & 7)) : (j ^ ((col >> 1) & 3));
      async16(B + ((size_t)ch * 128 + col) * KDIM + kg * 8, &Blds[b][(size_t)(g & ~63) * 8]);
    }
  };

#pragma unroll
  for (int i = 0; i < APT; ++i) {
    int g = i * 256 + tid;
    int col = g / KG, j = g % KG;
    int kg = (KG == 8) ? (j ^ (col & 7)) : (j ^ ((col >> 1) & 3));
    async16(A + (size_t)arow[i] * strideA + kg * 8, &Alds[(size_t)(g & ~63) * 8]);
  }
  stageB(chunk0, 0);
  __syncthreads();

  float s[16] = {};

  for (int cc = 0; cc < CPB; ++cc) {
    int ch = chunk0 + cc;
    bool valid = ch < nchunk;
    if (cc + 1 < CPB && chunk0 + cc + 1 < nchunk) stageB(chunk0 + cc + 1, (cc + 1) & 1);
    if (valid) {
      f32x4 acc[4][4] = {};
#pragma unroll
      for (int ks = 0; ks < KDIM / 32; ++ks) {
        bf16x8 af[4], bfr[4];
#pragma unroll
        for (int rt = 0; rt < 4; ++rt) {
          int rl = wr * 64 + rt * 16 + c;
          int kq = ks * 4 + q;
          int kg = (KG == 8) ? (kq ^ (rl & 7)) : (kq ^ ((rl >> 1) & 3));
          af[rt] = *(const bf16x8*)&Alds[((size_t)rl * KG + kg) * 8];
        }
#pragma unroll
        for (int ct = 0; ct < 4; ++ct) {
          int cl = wc * 64 + ct * 16 + c;
          int kq = ks * 4 + q;
          int kg = (KG == 8) ? (kq ^ (cl & 7)) : (kq ^ ((cl >> 1) & 3));
          bfr[ct] = *(const bf16x8*)&Blds[cc & 1][((size_t)cl * KG + kg) * 8];
        }
#pragma unroll
        for (int rt = 0; rt < 4; ++rt)
#pragma unroll
          for (int ct = 0; ct < 4; ++ct)
            acc[rt][ct] = mfma16x16x32(af[rt], bfr[ct], acc[rt][ct]);
      }
      float bv[4];
#pragma unroll
      for (int ct = 0; ct < 4; ++ct) {
        int colg = ch * 128 + wc * 64 + ct * 16 + c;
        bv[ct] = (colg < V) ? bias[colg] : -INFINITY;
      }
#pragma unroll
      for (int rt = 0; rt < 4; ++rt)
#pragma unroll
        for (int r = 0; r < 4; ++r)
          s[rt * 4 + r] += __expf(acc[rt][0][r] + bv[0]) + __expf(acc[rt][1][r] + bv[1]) +
                           __expf(acc[rt][2][r] + bv[2]) + __expf(acc[rt][3][r] + bv[3]);
    }
    __syncthreads();
  }

#pragma unroll
  for (int i = 0; i < 16; ++i) {
    float v = s[i];
#pragma unroll
    for (int off = 1; off <= 8; off <<= 1) v += __shfl_xor(v, off);
    if (c == 0) atomicAdd(&sums[row0 + wr * 64 + (i >> 2) * 16 + q * 4 + (i & 3)], v);
  }
}

// ---------------- final combine ----------------
__device__ __forceinline__ float wave_sum64(float v) {
#pragma unroll
  for (int off = 1; off < 64; off <<= 1) v += __shfl_xor(v, off);
  return v;
}
__device__ float dot_bw(const bf16* __restrict__ h, const float* __restrict__ wv, int K) {
  int lane = threadIdx.x & 63;
  float s = 0.f;
  for (int i = lane; i < K; i += 64) s += (float)h[i] * wv[i];
  return wave_sum64(s);
}

__global__ void __launch_bounds__(256) final_kernel(
    const int* __restrict__ target, const int* __restrict__ slotmap,
    const float* __restrict__ sumH, const float* __restrict__ sum1,
    const float* __restrict__ sum2, const float* __restrict__ sum3,
    const bf16* __restrict__ Hcat,
    const float* __restrict__ head_w, const float* __restrict__ head_b,
    const float* __restrict__ cluster_w, const float* __restrict__ cluster_b,
    const float* __restrict__ w1, const float* __restrict__ b1,
    const float* __restrict__ w2, const float* __restrict__ b2,
    const float* __restrict__ w3, const float* __restrict__ b3,
    float* __restrict__ out) {
  int wv = threadIdx.x >> 6, lane = threadIdx.x & 63;
  int row = blockIdx.x * 4 + wv;
  int t = target[row];
  const bf16* h0 = Hcat + (size_t)row * 1408;

  float lseH = __logf(sumH[row]);
  float lp;
  if (t < 20000) {
    float sel = dot_bw(h0, head_w + (size_t)t * 1024, 1024) + head_b[t];
    lp = sel - lseH;
  } else {
    int i, L, KW, hoff;
    const float* sp; const float* W; const float* Bb;
    if (t < 40000)        { i = 1; L = 20000;  KW = 256; hoff = 1024; sp = sum1; W = w1; Bb = b1; }
    else if (t < 200000)  { i = 2; L = 40000;  KW = 64;  hoff = 1280; sp = sum2; W = w2; Bb = b2; }
    else                  { i = 3; L = 200000; KW = 16;  hoff = 1344; sp = sum3; W = w3; Bb = b3; }
    int slot = slotmap[row];
    float lseT = __logf(sp[slot]);
    int ti = t - L;
    float tsel = dot_bw(h0 + hoff, W + (size_t)ti * KW, KW) + Bb[ti];
    int j = 3 - i;  // head_lp[:, -i] == cluster row (3-i)
    float csel = dot_bw(h0, cluster_w + (size_t)j * 1024, 1024) + cluster_b[j];
    lp = (csel - lseH) + (tsel - lseT);
  }
  if (lane == 0) out[row] = -lp;
}

extern "C" void kernel_launch(void* const* d_in, const int* in_sizes, int n_in,
                              void* d_out, int out_size, void* d_ws, size_t ws_size,
                              hipStream_t stream) {
  (void)in_sizes; (void)n_in; (void)out_size; (void)ws_size;
  const float* hidden    = (const float*)d_in[0];
  const int*   target    = (const int*)d_in[1];
  const float* head_w    = (const float*)d_in[2];
  const float* head_b    = (const float*)d_in[3];
  const float* cluster_w = (const float*)d_in[4];
  const float* cluster_b = (const float*)d_in[5];
  const float* proj0     = (const float*)d_in[6];
  const float* proj1     = (const float*)d_in[7];
  const float* proj2     = (const float*)d_in[8];
  const float* proj3     = (const float*)d_in[9];
  const float* w1 = (const float*)d_in[10];
  const float* b1 = (const float*)d_in[11];
  const float* w2 = (const float*)d_in[12];
  const float* b2 = (const float*)d_in[13];
  const float* w3 = (const float*)d_in[14];
  const float* b3 = (const float*)d_in[15];
  float* out = (float*)d_out;

  char* p = (char*)d_ws;
  bf16* hid_b = (bf16*)p; p += (size_t)1024 * 1024 * 2;
  bf16* Hcat  = (bf16*)p; p += (size_t)1024 * 1408 * 2;  // h0|h1|h2|h3 stride 1408
  bf16* Pcat  = (bf16*)p; p += (size_t)1408 * 1024 * 2;
  bf16* Wh    = (bf16*)p; p += (size_t)20096 * 1024 * 2; // head_w ++ cluster_w
  bf16* W1b   = (bf16*)p; p += (size_t)20096 * 256 * 2;
  bf16* W2b   = (bf16*)p; p += (size_t)160000 * 64 * 2;
  bf16* W3b   = (bf16*)p; p += (size_t)67840 * 32 * 2;
  float* sumH = (float*)p; p += 1024 * 4;
  float* sum1 = (float*)p; p += 1152 * 4;
  float* sum2 = (float*)p; p += 1152 * 4;
  float* sum3 = (float*)p; p += 1152 * 4;
  int* rowmap = (int*)p;  p += 3 * 1152 * 4;
  int* slotmap= (int*)p;  p += 1024 * 4;
  int* counts = (int*)p;  p += 3 * 4;

  compact_kernel<<<1, 1024, 0, stream>>>(target, rowmap, slotmap, counts, sumH);

  convert_all_kernel<<<36027, 256, 0, stream>>>(hidden, head_w, cluster_w, w1, w2,
                                                hid_b, Wh, W1b, W2b);
  convert_w3_kernel<<<1059, 256, 0, stream>>>(w3, W3b, 270940);
  transpose_all_kernel<<<dim3(32, 43), 256, 0, stream>>>(proj0, proj1, proj2, proj3, Pcat);

  // ---- all projections in one GEMM: Hcat[1024][1376] = hid_b @ Pcat^T ----
  gemm_kernel<1024, false><<<128, 256, 0, stream>>>(hid_b, 1024, nullptr, nullptr, Pcat,
                                                    nullptr, nullptr, 0, 0, nullptr, 11,
                                                    Hcat, 1408, 1376);

  // ---- fused GEMM + sumexp ----
  gemm_kernel<1024, true><<<64 * 20, 256, 0, stream>>>(Hcat, 1408, nullptr, nullptr, Wh,
                                                       head_b, cluster_b, 20000, 20003,
                                                       sumH, 157, nullptr, 0, 0);
  gemm_kernel<256, true><<<64 * 20, 256, 0, stream>>>(Hcat + 1024, 1408, rowmap, counts, W1b,
                                                      b1, b1, 0x40000000, 20000,
                                                      sum1, 157, nullptr, 0, 0);
  tail_lse_kernel<64, 5><<<64 * 32, 256, 0, stream>>>(Hcat + 1280, 1408, rowmap + 1152,
                                                      counts + 1, W2b, b2, 160000, sum2, 1250);
  tail_lse_kernel<32, 4><<<64 * 17, 256, 0, stream>>>(Hcat + 1344, 1408, rowmap + 2304,
                                                      counts + 2, W3b, b3, 67735, sum3, 530);

  final_kernel<<<256, 256, 0, stream>>>(target, slotmap, sumH, sum1, sum2, sum3, Hcat,
                                        head_w, head_b, cluster_w, cluster_b,
                                        w1, b1, w2, b2, w3, b3, out);
}